// Round 4
// baseline (2592.506 us; speedup 1.0000x reference)
//
#include <hip/hip_runtime.h>
#include <hip/hip_bf16.h>
#include <stdint.h>

#define DIM 4096
#define NB 4
#define SEQ 2048

typedef __bf16 bf16_t;
typedef __bf16 bf16x8 __attribute__((ext_vector_type(8)));
typedef float f32x4 __attribute__((ext_vector_type(4)));

__device__ __forceinline__ uint16_t f2bf_u(float f) {
  union { float f; uint32_t u; } v; v.f = f;
  uint32_t r = v.u + 0x7FFFu + ((v.u >> 16) & 1u);
  return (uint16_t)(r >> 16);
}

// ---------------- fp32 -> bf16 conversion ----------------
__global__ __launch_bounds__(256) void cvt_f32_bf16_k(const float* __restrict__ in,
                                                      uint16_t* __restrict__ out, long n) {
  long i = ((long)blockIdx.x * 256 + threadIdx.x) * 8;
  long stride = (long)gridDim.x * 256 * 8;
  for (; i < n; i += stride) {
    float4 a = *(const float4*)(in + i);
    float4 b = *(const float4*)(in + i + 4);
    ushort4 o0 = make_ushort4(f2bf_u(a.x), f2bf_u(a.y), f2bf_u(a.z), f2bf_u(a.w));
    ushort4 o1 = make_ushort4(f2bf_u(b.x), f2bf_u(b.y), f2bf_u(b.z), f2bf_u(b.w));
    *(ushort4*)(out + i) = o0;
    *(ushort4*)(out + i + 4) = o1;
  }
}

// ---------------- async global->LDS ----------------
__device__ __forceinline__ void gload16(const void* g, void* l) {
  __builtin_amdgcn_global_load_lds(
      (const __attribute__((address_space(1))) void*)g,
      (__attribute__((address_space(3))) void*)l,
      16, 0, 0);
}

#define BARX() do { asm volatile("" ::: "memory"); __builtin_amdgcn_s_barrier(); asm volatile("" ::: "memory"); } while (0)
#define VMW(n) asm volatile("s_waitcnt vmcnt(" #n ")" ::: "memory")

__device__ __forceinline__ void readA(bf16x8 (&fa)[4][2], const char* p, int c0, int c1) {
#pragma unroll
  for (int m = 0; m < 4; ++m) {
    fa[m][0] = *(const bf16x8*)(p + m * 2048 + c0);
    fa[m][1] = *(const bf16x8*)(p + m * 2048 + c1);
  }
}
__device__ __forceinline__ void readB(bf16x8 (&fb)[2][2], const char* p, int c0, int c1) {
#pragma unroll
  for (int n = 0; n < 2; ++n) {
    fb[n][0] = *(const bf16x8*)(p + n * 2048 + c0);
    fb[n][1] = *(const bf16x8*)(p + n * 2048 + c1);
  }
}
__device__ __forceinline__ void mmaQ(f32x4 (&acc)[4][2], const bf16x8 (&fa)[4][2],
                                     const bf16x8 (&fb)[2][2]) {
#pragma unroll
  for (int m = 0; m < 4; ++m)
#pragma unroll
    for (int n = 0; n < 2; ++n)
#pragma unroll
      for (int kk = 0; kk < 2; ++kk)
        acc[m][n] = __builtin_amdgcn_mfma_f32_16x16x32_bf16(fa[m][kk], fb[n][kk], acc[m][n], 0, 0, 0);
}
__device__ __forceinline__ void stageH(const bf16_t* gt, int soff, long rsk, char* lb, int t16) {
  gload16(gt + soff, lb + t16);
  gload16(gt + soff + rsk, lb + 8192 + t16);
}

#define PRIO1() __builtin_amdgcn_s_setprio(1)
#define PRIO0() __builtin_amdgcn_s_setprio(0)

// ---------------- 256x256 8-phase PIPELINED bf16 GEMM: C[m][n] = sum_k A[m][k]*B[n][k] ----
// Fragment reads issued one phase ahead of their MFMA (reads overlap compute);
// one barrier per phase; counted vmcnt ledger guards every staged region.
// EPI 0: bf16 out  1: fp32 out  2: bf16( Xadd + silu(acc) )
template <int EPI>
__global__ __launch_bounds__(512, 2) void gemm256(
    const bf16_t* __restrict__ Abase, const bf16_t* __restrict__ Bbase,
    void* __restrict__ Cout, const float* __restrict__ Xadd,
    int M, int N, int K, long sA, long sB, long sC) {
  __shared__ char smem[131072];
  char* As = smem;            // [2 buf][2 half][128 rows][64 cols] bf16
  char* Bs = smem + 65536;

  const int tid = threadIdx.x;
  const int lane = tid & 63;
  const int wave = tid >> 6;
  const int wm = wave >> 2;   // 0..1  (row stripe)
  const int wn = wave & 3;    // 0..3  (col stripe)
  const int lr = lane & 15;
  const int hi = lane >> 4;

  // bijective XCD swizzle (all our grids are %8==0)
  const int nwg = gridDim.x;
  int wg = blockIdx.x;
  if ((nwg & 7) == 0) wg = (wg & 7) * (nwg >> 3) + (wg >> 3);
  const int nbn = N >> 8;
  const int bm = wg / nbn, bn = wg % nbn;

  const bf16_t* A = Abase + (long)blockIdx.y * sA;
  const bf16_t* B = Bbase + (long)blockIdx.y * sB;
  const bf16_t* A0p = A + (long)(bm * 256) * K;
  const bf16_t* A1p = A0p + (long)128 * K;
  const bf16_t* B0p = B + (long)(bn * 256) * K;
  const bf16_t* B1p = B0p + (long)128 * K;
  const long rsk = (long)64 * K;

  // staging: linear LDS dest, inverse-swizzled global source (3-bit XOR involution)
  const int t16 = tid * 16;
  const int lp = t16 ^ (((t16 >> 7) & 7) << 4);
  const int soff = (lp >> 7) * K + ((lp & 127) >> 1);

  // frag read addressing: row base + swizzled column (kk step applied via XOR 64)
  const int swz = (lr & 7) << 4;
  const int c0 = (hi * 16) ^ swz;
  const int c1 = c0 ^ 64;
  const int aR = (wm * 64 + lr) * 128;
  const int bR = (wn * 32 + lr) * 128;

  f32x4 acc[2][2][4][2] = {};
  bf16x8 fa0[4][2], fa1[4][2], fb0[2][2], fb1[2][2];

  // prologue: tile0 -> buf0 (4 halves), tile1 -> buf1 (A0,A1,B0). buf1.B1 staged in ph1.
  stageH(A0p, soff, rsk, As, t16);             // buf0.A0
  stageH(A1p, soff, rsk, As + 16384, t16);     // buf0.A1
  stageH(B0p, soff, rsk, Bs, t16);             // buf0.B0
  stageH(B1p, soff, rsk, Bs + 16384, t16);     // buf0.B1
  stageH(A0p + 64, soff, rsk, As + 32768, t16);  // buf1.A0
  stageH(A1p + 64, soff, rsk, As + 49152, t16);  // buf1.A1
  stageH(B0p + 64, soff, rsk, Bs + 32768, t16);  // buf1.B0
  VMW(6);   // buf0 fully landed (oldest 8 of 14)
  BARX();
  readA(fa0, As + aR, c0, c1);
  readB(fb0, Bs + bR, c0, c1);

  const int NIT = K >> 7;   // 2 K-tiles (of 64) per iteration
  for (int i = 0; i < NIT; ++i) {
    const bool last = (i == NIT - 1);
    const int k1 = (2 * i + 1) * 64;
    // ph1: M(0,0)b0 ; R fb1<-buf0.B1 ; S1 b1.B1 <- tile(2i+1)
    readB(fb1, Bs + 16384 + bR, c0, c1);
    stageH(B1p + k1, soff, rsk, Bs + 49152, t16);
    PRIO1(); mmaQ(acc[0][0], fa0, fb0); PRIO0();
    BARX();
    // ph2: M(0,1)b0 ; R fa1<-buf0.A1 ; S2 b0.A0 <- tile(2i+2)
    readA(fa1, As + 16384 + aR, c0, c1);
    if (!last) stageH(A0p + k1 + 64, soff, rsk, As, t16);
    PRIO1(); mmaQ(acc[0][1], fa0, fb1); PRIO0();
    if (last) { VMW(0); } else { VMW(8); }   // guard prev-S6 (buf1.A0) for ph3
    BARX();
    // ph3: M(1,0)b0 ; R fa0<-buf1.A0 ; S3 b0.A1
    readA(fa0, As + 32768 + aR, c0, c1);
    if (!last) stageH(A1p + k1 + 64, soff, rsk, As + 16384, t16);
    PRIO1(); mmaQ(acc[1][0], fa1, fb0); PRIO0();
    if (!last) VMW(6);                        // guard prev-S8 (buf1.B0) for ph4
    BARX();
    // ph4: M(1,1)b0 ; R fb0<-buf1.B0 ; S4 b0.B0
    readB(fb0, Bs + 32768 + bR, c0, c1);
    if (!last) stageH(B0p + k1 + 64, soff, rsk, Bs, t16);
    PRIO1(); mmaQ(acc[1][1], fa1, fb1); PRIO0();
    if (!last) VMW(6);                        // guard S1 (buf1.B1) for ph5
    BARX();
    // ph5: M(0,0)b1 ; R fb1<-buf1.B1 ; S5 b0.B1
    readB(fb1, Bs + 49152 + bR, c0, c1);
    if (!last) stageH(B1p + k1 + 64, soff, rsk, Bs + 16384, t16);
    PRIO1(); mmaQ(acc[0][0], fa0, fb0); PRIO0();
    BARX();
    // ph6: M(0,1)b1 ; R fa1<-buf1.A1 ; S6 b1.A0 <- tile(2i+3)
    readA(fa1, As + 49152 + aR, c0, c1);
    if (!last) stageH(A0p + k1 + 128, soff, rsk, As + 32768, t16);
    PRIO1(); mmaQ(acc[0][1], fa0, fb1); PRIO0();
    if (!last) VMW(8);                        // guard S2 (buf0.A0) for ph7
    BARX();
    // ph7: M(1,0)b1 ; R fa0<-buf0.A0 (next tile) ; S7 b1.A1
    if (!last) readA(fa0, As + aR, c0, c1);
    if (!last) stageH(A1p + k1 + 128, soff, rsk, As + 49152, t16);
    PRIO1(); mmaQ(acc[1][0], fa1, fb0); PRIO0();
    if (!last) VMW(6);                        // guard S4 (buf0.B0) for ph8
    BARX();
    // ph8: M(1,1)b1 ; R fb0<-buf0.B0 ; S8 b1.B0
    if (!last) readB(fb0, Bs + bR, c0, c1);
    if (!last) stageH(B0p + k1 + 128, soff, rsk, Bs + 32768, t16);
    PRIO1(); mmaQ(acc[1][1], fa1, fb1); PRIO0();
    if (!last) VMW(6);                        // guard S5 (buf0.B1) for next ph1
    BARX();
  }

  // epilogue: frag elem j -> row += j (D-layout: col=lane&15, row=(lane>>4)*4+j)
  const long cb = (long)blockIdx.y * sC;
#pragma unroll
  for (int mh = 0; mh < 2; ++mh)
#pragma unroll
    for (int nh = 0; nh < 2; ++nh)
#pragma unroll
      for (int m = 0; m < 4; ++m)
#pragma unroll
        for (int n = 0; n < 2; ++n)
#pragma unroll
          for (int j = 0; j < 4; ++j) {
            const int row = bm * 256 + mh * 128 + wm * 64 + m * 16 + hi * 4 + j;
            const int col = bn * 256 + nh * 128 + wn * 32 + n * 16 + lr;
            const long idx = cb + (long)row * N + col;
            const float vv = acc[mh][nh][m][n][j];
            if constexpr (EPI == 0) {
              ((uint16_t*)Cout)[idx] = f2bf_u(vv);
            } else if constexpr (EPI == 1) {
              ((float*)Cout)[idx] = vv;
            } else {
              const float sl = vv / (1.f + __expf(-vv));
              ((uint16_t*)Cout)[idx] = f2bf_u(Xadd[idx] + sl);
            }
          }
}

// ---------------- row softmax (4096 wide, fp32 -> bf16) ----------------
__global__ __launch_bounds__(256) void softmax_row4096(const float* __restrict__ in,
                                                       uint16_t* __restrict__ out) {
  const long row = blockIdx.x;
  const float* r = in + row * 4096;
  const int tid = threadIdx.x;
  float v[16];
#pragma unroll
  for (int i = 0; i < 4; ++i) {
    float4 a = *(const float4*)(r + tid * 16 + i * 4);
    v[i * 4 + 0] = a.x; v[i * 4 + 1] = a.y; v[i * 4 + 2] = a.z; v[i * 4 + 3] = a.w;
  }
  float m = v[0];
#pragma unroll
  for (int j = 1; j < 16; ++j) m = fmaxf(m, v[j]);
#pragma unroll
  for (int o = 32; o; o >>= 1) m = fmaxf(m, __shfl_xor(m, o));
  __shared__ float red[8];
  if ((tid & 63) == 0) red[tid >> 6] = m;
  __syncthreads();
  m = fmaxf(fmaxf(red[0], red[1]), fmaxf(red[2], red[3]));
  float s = 0.f;
#pragma unroll
  for (int j = 0; j < 16; ++j) { v[j] = __expf(v[j] - m); s += v[j]; }
#pragma unroll
  for (int o = 32; o; o >>= 1) s += __shfl_xor(s, o);
  if ((tid & 63) == 0) red[4 + (tid >> 6)] = s;
  __syncthreads();
  s = (red[4] + red[5]) + (red[6] + red[7]);
  float inv = 1.f / s;
#pragma unroll
  for (int i = 0; i < 4; ++i) {
    ushort4 u = make_ushort4(f2bf_u(v[i * 4 + 0] * inv), f2bf_u(v[i * 4 + 1] * inv),
                             f2bf_u(v[i * 4 + 2] * inv), f2bf_u(v[i * 4 + 3] * inv));
    *(ushort4*)(out + row * 4096 + tid * 16 + i * 4) = u;
  }
}

// ---------------- per-row (max, 1/sum(exp)) stats ----------------
__global__ __launch_bounds__(256) void rowstat4096(const float* __restrict__ in,
                                                   float2* __restrict__ stats) {
  const long row = blockIdx.x;
  const float* r = in + row * 4096;
  const int tid = threadIdx.x;
  float v[16];
#pragma unroll
  for (int i = 0; i < 4; ++i) {
    float4 a = *(const float4*)(r + tid * 16 + i * 4);
    v[i * 4 + 0] = a.x; v[i * 4 + 1] = a.y; v[i * 4 + 2] = a.z; v[i * 4 + 3] = a.w;
  }
  float m = v[0];
#pragma unroll
  for (int j = 1; j < 16; ++j) m = fmaxf(m, v[j]);
#pragma unroll
  for (int o = 32; o; o >>= 1) m = fmaxf(m, __shfl_xor(m, o));
  __shared__ float red[8];
  if ((tid & 63) == 0) red[tid >> 6] = m;
  __syncthreads();
  m = fmaxf(fmaxf(red[0], red[1]), fmaxf(red[2], red[3]));
  float s = 0.f;
#pragma unroll
  for (int j = 0; j < 16; ++j) s += __expf(v[j] - m);
#pragma unroll
  for (int o = 32; o; o >>= 1) s += __shfl_xor(s, o);
  if ((tid & 63) == 0) red[4 + (tid >> 6)] = s;
  __syncthreads();
  if (tid == 0) {
    s = (red[4] + red[5]) + (red[6] + red[7]);
    stats[row] = make_float2(m, 1.f / s);
  }
}

// ---------------- fused softmax + transpose: out[e][d] = sm(in)[d][e] ----------------
__global__ __launch_bounds__(256) void transposeSM(const float* __restrict__ in,
                                                   const float2* __restrict__ stats,
                                                   uint16_t* __restrict__ out) {
  __shared__ uint16_t t[64][68];
  __shared__ float2 st[64];
  const int tid = threadIdx.x;
  const int bx = blockIdx.x, by = blockIdx.y;
  if (tid < 64) st[tid] = stats[by * 64 + tid];
  __syncthreads();
  const int tr = tid >> 4;
  const int tc4 = (tid & 15) * 4;
#pragma unroll
  for (int i = 0; i < 4; ++i) {
    const int r = tr + i * 16;
    const float2 ms = st[r];
    float4 v = *(const float4*)&in[(long)(by * 64 + r) * 4096 + bx * 64 + tc4];
    t[r][tc4 + 0] = f2bf_u(__expf(v.x - ms.x) * ms.y);
    t[r][tc4 + 1] = f2bf_u(__expf(v.y - ms.x) * ms.y);
    t[r][tc4 + 2] = f2bf_u(__expf(v.z - ms.x) * ms.y);
    t[r][tc4 + 3] = f2bf_u(__expf(v.w - ms.x) * ms.y);
  }
  __syncthreads();
#pragma unroll
  for (int i = 0; i < 4; ++i) {
    const int oc = tr + i * 16;
    ushort4 v = make_ushort4(t[tc4 + 0][oc], t[tc4 + 1][oc], t[tc4 + 2][oc], t[tc4 + 3][oc]);
    *(ushort4*)&out[(long)(bx * 64 + oc) * 4096 + by * 64 + tc4] = v;
  }
}

// ---------------- host ----------------
extern "C" void kernel_launch(void* const* d_in, const int* in_sizes, int n_in,
                              void* d_out, int out_size, void* d_ws, size_t ws_size,
                              hipStream_t stream) {
  const float* x  = (const float*)d_in[0];
  const float* W1 = (const float*)d_in[1];
  const float* W2 = (const float*)d_in[2];
  const float* W3 = (const float*)d_in[3];
  const float* W4 = (const float*)d_in[4];
  const float* Wo = (const float*)d_in[5];

  char* ws = (char*)d_ws;
  const long SD  = (long)SEQ * DIM;
  const long BSD = (long)NB * SD;
  const long DD  = (long)DIM * DIM;

  // workspace layout (436,207,616 bytes == proven footprint)
  bf16_t* xbf  = (bf16_t*)(ws + 0L);           // x bf16; later y_in bf16
  bf16_t* xAT  = (bf16_t*)(ws + 67108864L);    // xA^T [b][d][s]
  bf16_t* xBT  = (bf16_t*)(ws + 134217728L);   // xB^T [b][e][s]; later xO_sm
  void*   R3   = (void*)  (ws + 201326592L);   // SQ fp32 (per batch); later xC bf16
  bf16_t* Wbf  = (bf16_t*)(ws + 268435456L);   // current weight bf16
  bf16_t* sqmT = (bf16_t*)(ws + 301989888L);   // softmax(sq)^T bf16 [4][e][d]
  float2* stats = (float2*)d_out;              // transient per-batch row stats
  float*  xOraw = (float*)d_out;               // xO raw fp32 (full d_out)
  (void)ws_size; (void)in_sizes; (void)n_in; (void)out_size;

  cvt_f32_bf16_k<<<2048, 256, 0, stream>>>(x, (uint16_t*)xbf, BSD);

  // xA^T[b][d][s] = W1 @ x_b^T   (batched, grid.y = 4)
  cvt_f32_bf16_k<<<2048, 256, 0, stream>>>(W1, (uint16_t*)Wbf, DD);
  gemm256<0><<<dim3(128, 4), 512, 0, stream>>>(Wbf, xbf, (void*)xAT, nullptr,
                                               DIM, SEQ, DIM, 0, SD, SD);
  // xB^T
  cvt_f32_bf16_k<<<2048, 256, 0, stream>>>(W2, (uint16_t*)Wbf, DD);
  gemm256<0><<<dim3(128, 4), 512, 0, stream>>>(Wbf, xbf, (void*)xBT, nullptr,
                                               DIM, SEQ, DIM, 0, SD, SD);

  // per batch: SQ = xA^T @ xB, softmax rows, transposed bf16 -> sqmT[b]
  for (int b = 0; b < NB; ++b) {
    gemm256<1><<<dim3(256, 1), 512, 0, stream>>>(xAT + b * SD, xBT + b * SD, R3, nullptr,
                                                 DIM, DIM, SEQ, 0, 0, 0);
    rowstat4096<<<DIM, 256, 0, stream>>>((const float*)R3, stats);
    transposeSM<<<dim3(64, 64), 256, 0, stream>>>((const float*)R3, stats,
                                                  (uint16_t*)(sqmT + b * DD));
  }

  // xC = x @ W3^T  (batch folded into M) -> R3 (SQ scratch dead)
  cvt_f32_bf16_k<<<2048, 256, 0, stream>>>(W3, (uint16_t*)Wbf, DD);
  gemm256<0><<<dim3(512, 1), 512, 0, stream>>>(xbf, Wbf, R3, nullptr,
                                               NB * SEQ, DIM, DIM, 0, 0, 0);

  // xO[b][s][e] = xC_b @ sqmT_b^T  (batched) -> d_out fp32 scratch
  gemm256<1><<<dim3(128, 4), 512, 0, stream>>>((const bf16_t*)R3, sqmT, (void*)xOraw, nullptr,
                                               SEQ, DIM, DIM, SD, DD, SD);
  // softmax rows of xO -> xO_sm bf16 (overwrites xBT)
  softmax_row4096<<<NB * SEQ, 256, 0, stream>>>(xOraw, (uint16_t*)xBT);

  // y_in = bf16( x + silu(xO_sm @ W4^T) ) -> xbf region
  cvt_f32_bf16_k<<<2048, 256, 0, stream>>>(W4, (uint16_t*)Wbf, DD);
  gemm256<2><<<dim3(512, 1), 512, 0, stream>>>(xBT, Wbf, (void*)xbf, x,
                                               NB * SEQ, DIM, DIM, 0, 0, 0);

  // out = y_in @ Wo^T (fp32)
  cvt_f32_bf16_k<<<2048, 256, 0, stream>>>(Wo, (uint16_t*)Wbf, DD);
  gemm256<1><<<dim3(512, 1), 512, 0, stream>>>(xbf, Wbf, d_out, nullptr,
                                               NB * SEQ, DIM, DIM, 0, 0, 0);
}

// Round 5
// 1827.015 us; speedup vs baseline: 1.4190x; 1.4190x over previous
//
#include <hip/hip_runtime.h>
#include <hip/hip_bf16.h>
#include <stdint.h>

#define DIM 4096
#define NB 4
#define SEQ 2048

typedef __bf16 bf16_t;
typedef __bf16 bf16x8 __attribute__((ext_vector_type(8)));
typedef float f32x4 __attribute__((ext_vector_type(4)));

__device__ __forceinline__ uint16_t f2bf_u(float f) {
  union { float f; uint32_t u; } v; v.f = f;
  uint32_t r = v.u + 0x7FFFu + ((v.u >> 16) & 1u);
  return (uint16_t)(r >> 16);
}

// ---------------- fp32 -> bf16 conversion ----------------
__global__ __launch_bounds__(256) void cvt_f32_bf16_k(const float* __restrict__ in,
                                                      uint16_t* __restrict__ out, long n) {
  long i = ((long)blockIdx.x * 256 + threadIdx.x) * 8;
  long stride = (long)gridDim.x * 256 * 8;
  for (; i < n; i += stride) {
    float4 a = *(const float4*)(in + i);
    float4 b = *(const float4*)(in + i + 4);
    ushort4 o0 = make_ushort4(f2bf_u(a.x), f2bf_u(a.y), f2bf_u(a.z), f2bf_u(a.w));
    ushort4 o1 = make_ushort4(f2bf_u(b.x), f2bf_u(b.y), f2bf_u(b.z), f2bf_u(b.w));
    *(ushort4*)(out + i) = o0;
    *(ushort4*)(out + i + 4) = o1;
  }
}

// ---------------- async global->LDS ----------------
__device__ __forceinline__ void gload16(const void* g, void* l) {
  __builtin_amdgcn_global_load_lds(
      (const __attribute__((address_space(1))) void*)g,
      (__attribute__((address_space(3))) void*)l,
      16, 0, 0);
}

#define BARX() do { asm volatile("" ::: "memory"); __builtin_amdgcn_s_barrier(); asm volatile("" ::: "memory"); } while (0)
#define VMW(n) asm volatile("s_waitcnt vmcnt(" #n ")" ::: "memory")

__device__ __forceinline__ void readA(bf16x8 (&fa)[4][2], const char* p, int c0, int c1) {
#pragma unroll
  for (int m = 0; m < 4; ++m) {
    fa[m][0] = *(const bf16x8*)(p + m * 2048 + c0);
    fa[m][1] = *(const bf16x8*)(p + m * 2048 + c1);
  }
}
__device__ __forceinline__ void readB(bf16x8 (&fb)[2][2], const char* p, int c0, int c1) {
#pragma unroll
  for (int n = 0; n < 2; ++n) {
    fb[n][0] = *(const bf16x8*)(p + n * 2048 + c0);
    fb[n][1] = *(const bf16x8*)(p + n * 2048 + c1);
  }
}
__device__ __forceinline__ void mmaQ(f32x4 (&acc)[4][2], const bf16x8 (&fa)[4][2],
                                     const bf16x8 (&fb)[2][2]) {
#pragma unroll
  for (int m = 0; m < 4; ++m)
#pragma unroll
    for (int n = 0; n < 2; ++n)
#pragma unroll
      for (int kk = 0; kk < 2; ++kk)
        acc[m][n] = __builtin_amdgcn_mfma_f32_16x16x32_bf16(fa[m][kk], fb[n][kk], acc[m][n], 0, 0, 0);
}
__device__ __forceinline__ void stageH(const bf16_t* gt, int soff, long rsk, char* lb, int t16) {
  gload16(gt + soff, lb + t16);
  gload16(gt + soff + rsk, lb + 8192 + t16);
}

#define PRIO1() __builtin_amdgcn_s_setprio(1)
#define PRIO0() __builtin_amdgcn_s_setprio(0)

// ---------------- 256x256 4-region bf16 GEMM: C[m][n] = sum_k A[m][k]*B[n][k] ----------------
// BM=BN=256, BK=64, 8 waves (2M x 4N), LDS 128KB double-buffered, 3-bit XOR swizzle.
// Region = [reads ; stages ; 32 MFMA ; VMW(8) ; barrier] -- no mid-barrier; each read is
// consumed by an MFMA within its region, so lgkm is drained before the end-barrier, making
// one barrier per region sufficient for all LDS WAR hazards. Counted vmcnt ledger:
// steady-state VMW(8) everywhere; prologue VMW(6); last iter VMW(2)/VMW(0) at B/C.
// EPI 0: bf16 out  1: fp32 out  2: bf16( Xadd + silu(acc) )
template <int EPI>
__global__ __launch_bounds__(512, 2) void gemm256(
    const bf16_t* __restrict__ Abase, const bf16_t* __restrict__ Bbase,
    void* __restrict__ Cout, const float* __restrict__ Xadd,
    int M, int N, int K, long sA, long sB, long sC) {
  __shared__ char smem[131072];
  char* As = smem;            // [2 buf][2 half][128 rows][64 cols] bf16
  char* Bs = smem + 65536;

  const int tid = threadIdx.x;
  const int lane = tid & 63;
  const int wave = tid >> 6;
  const int wm = wave >> 2;   // 0..1  (row stripe)
  const int wn = wave & 3;    // 0..3  (col stripe)
  const int lr = lane & 15;
  const int hi = lane >> 4;

  // bijective XCD swizzle (all our grids are %8==0)
  const int nwg = gridDim.x;
  int wg = blockIdx.x;
  if ((nwg & 7) == 0) wg = (wg & 7) * (nwg >> 3) + (wg >> 3);
  const int nbn = N >> 8;
  const int bm = wg / nbn, bn = wg % nbn;

  const bf16_t* A = Abase + (long)blockIdx.y * sA;
  const bf16_t* B = Bbase + (long)blockIdx.y * sB;
  const bf16_t* A0p = A + (long)(bm * 256) * K;
  const bf16_t* A1p = A0p + (long)128 * K;
  const bf16_t* B0p = B + (long)(bn * 256) * K;
  const bf16_t* B1p = B0p + (long)128 * K;
  const long rsk = (long)64 * K;

  // staging: linear LDS dest, inverse-swizzled global source (3-bit XOR involution)
  const int t16 = tid * 16;
  const int lp = t16 ^ (((t16 >> 7) & 7) << 4);
  const int soff = (lp >> 7) * K + ((lp & 127) >> 1);

  // frag read addressing: row base + swizzled column (kk step applied via XOR 64)
  const int swz = (lr & 7) << 4;
  const int c0 = (hi * 16) ^ swz;
  const int c1 = c0 ^ 64;
  const int aR = (wm * 64 + lr) * 128;
  const int bR = (wn * 32 + lr) * 128;

  f32x4 acc[2][2][4][2] = {};
  bf16x8 fa0[4][2], fa1[4][2], fb0[2][2], fb1[2][2];

  // prologue: tile0 -> buf0 (4 halves), tile1 -> buf1 (A0,A1,B0). buf1.B1 staged in region A.
  stageH(A0p, soff, rsk, As, t16);               // buf0.A0
  stageH(A1p, soff, rsk, As + 16384, t16);       // buf0.A1
  stageH(B0p, soff, rsk, Bs, t16);               // buf0.B0
  stageH(B1p, soff, rsk, Bs + 16384, t16);       // buf0.B1
  stageH(A0p + 64, soff, rsk, As + 32768, t16);  // buf1.A0
  stageH(A1p + 64, soff, rsk, As + 49152, t16);  // buf1.A1
  stageH(B0p + 64, soff, rsk, Bs + 32768, t16);  // buf1.B0
  VMW(6);   // buf0 (oldest 8 of 14) landed
  BARX();

  const int NIT = K >> 7;   // 2 K-tiles (of 64) per iteration
  for (int i = 0; i < NIT; ++i) {
    const bool last = (i == NIT - 1);
    const int k1 = (2 * i + 1) * 64;  // buf1 K-offset (this iter)
    const int k2 = k1 + 64;           // next buf0 tile
    const int k3 = k1 + 128;          // next buf1 tile

    // ---- region A: buf0, N-half0 quadrants ----
    readA(fa0, As + aR, c0, c1);
    readB(fb0, Bs + bR, c0, c1);
    readA(fa1, As + 16384 + aR, c0, c1);
    stageH(B1p + k1, soff, rsk, Bs + 49152, t16);          // S1: b1.B1
    PRIO1(); mmaQ(acc[0][0], fa0, fb0); mmaQ(acc[1][0], fa1, fb0); PRIO0();
    VMW(8);                                                // retires prev-S5 (b0.B1)
    BARX();
    // ---- region B: buf0, N-half1 ----
    readB(fb1, Bs + 16384 + bR, c0, c1);
    if (!last) {
      stageH(A0p + k2, soff, rsk, As, t16);                // S2: b0.A0
      stageH(A1p + k2, soff, rsk, As + 16384, t16);        // S3: b0.A1
      stageH(B0p + k2, soff, rsk, Bs, t16);                // S4: b0.B0
    }
    PRIO1(); mmaQ(acc[0][1], fa0, fb1); mmaQ(acc[1][1], fa1, fb1); PRIO0();
    if (last) { VMW(2); } else { VMW(8); }                 // retires prev-S6..S8 (buf1 trio)
    BARX();
    // ---- region C: buf1, N-half0 ----
    readA(fa0, As + 32768 + aR, c0, c1);
    readB(fb0, Bs + 32768 + bR, c0, c1);
    readA(fa1, As + 49152 + aR, c0, c1);
    if (!last) stageH(B1p + k2, soff, rsk, Bs + 16384, t16); // S5: b0.B1
    PRIO1(); mmaQ(acc[0][0], fa0, fb0); mmaQ(acc[1][0], fa1, fb0); PRIO0();
    if (last) { VMW(0); } else { VMW(8); }                 // retires S1 (b1.B1)
    BARX();
    // ---- region D: buf1, N-half1 ----
    readB(fb1, Bs + 49152 + bR, c0, c1);
    if (!last) {
      stageH(A0p + k3, soff, rsk, As + 32768, t16);        // S6: b1.A0
      stageH(A1p + k3, soff, rsk, As + 49152, t16);        // S7: b1.A1
      stageH(B0p + k3, soff, rsk, Bs + 32768, t16);        // S8: b1.B0
    }
    PRIO1(); mmaQ(acc[0][1], fa0, fb1); mmaQ(acc[1][1], fa1, fb1); PRIO0();
    if (!last) VMW(8);                                     // retires S2..S4 (next buf0)
    BARX();
  }

  // epilogue: frag elem j -> row += j (D-layout: col=lane&15, row=(lane>>4)*4+j)
  const long cb = (long)blockIdx.y * sC;
#pragma unroll
  for (int mh = 0; mh < 2; ++mh)
#pragma unroll
    for (int nh = 0; nh < 2; ++nh)
#pragma unroll
      for (int m = 0; m < 4; ++m)
#pragma unroll
        for (int n = 0; n < 2; ++n)
#pragma unroll
          for (int j = 0; j < 4; ++j) {
            const int row = bm * 256 + mh * 128 + wm * 64 + m * 16 + hi * 4 + j;
            const int col = bn * 256 + nh * 128 + wn * 32 + n * 16 + lr;
            const long idx = cb + (long)row * N + col;
            const float vv = acc[mh][nh][m][n][j];
            if constexpr (EPI == 0) {
              ((uint16_t*)Cout)[idx] = f2bf_u(vv);
            } else if constexpr (EPI == 1) {
              ((float*)Cout)[idx] = vv;
            } else {
              const float sl = vv / (1.f + __expf(-vv));
              ((uint16_t*)Cout)[idx] = f2bf_u(Xadd[idx] + sl);
            }
          }
}

// ---------------- row softmax (4096 wide, fp32 -> bf16) ----------------
__global__ __launch_bounds__(256) void softmax_row4096(const float* __restrict__ in,
                                                       uint16_t* __restrict__ out) {
  const long row = blockIdx.x;
  const float* r = in + row * 4096;
  const int tid = threadIdx.x;
  float v[16];
#pragma unroll
  for (int i = 0; i < 4; ++i) {
    float4 a = *(const float4*)(r + tid * 16 + i * 4);
    v[i * 4 + 0] = a.x; v[i * 4 + 1] = a.y; v[i * 4 + 2] = a.z; v[i * 4 + 3] = a.w;
  }
  float m = v[0];
#pragma unroll
  for (int j = 1; j < 16; ++j) m = fmaxf(m, v[j]);
#pragma unroll
  for (int o = 32; o; o >>= 1) m = fmaxf(m, __shfl_xor(m, o));
  __shared__ float red[8];
  if ((tid & 63) == 0) red[tid >> 6] = m;
  __syncthreads();
  m = fmaxf(fmaxf(red[0], red[1]), fmaxf(red[2], red[3]));
  float s = 0.f;
#pragma unroll
  for (int j = 0; j < 16; ++j) { v[j] = __expf(v[j] - m); s += v[j]; }
#pragma unroll
  for (int o = 32; o; o >>= 1) s += __shfl_xor(s, o);
  if ((tid & 63) == 0) red[4 + (tid >> 6)] = s;
  __syncthreads();
  s = (red[4] + red[5]) + (red[6] + red[7]);
  float inv = 1.f / s;
#pragma unroll
  for (int i = 0; i < 4; ++i) {
    ushort4 u = make_ushort4(f2bf_u(v[i * 4 + 0] * inv), f2bf_u(v[i * 4 + 1] * inv),
                             f2bf_u(v[i * 4 + 2] * inv), f2bf_u(v[i * 4 + 3] * inv));
    *(ushort4*)(out + row * 4096 + tid * 16 + i * 4) = u;
  }
}

// ---------------- per-row (max, 1/sum(exp)) stats ----------------
__global__ __launch_bounds__(256) void rowstat4096(const float* __restrict__ in,
                                                   float2* __restrict__ stats) {
  const long row = blockIdx.x;
  const float* r = in + row * 4096;
  const int tid = threadIdx.x;
  float v[16];
#pragma unroll
  for (int i = 0; i < 4; ++i) {
    float4 a = *(const float4*)(r + tid * 16 + i * 4);
    v[i * 4 + 0] = a.x; v[i * 4 + 1] = a.y; v[i * 4 + 2] = a.z; v[i * 4 + 3] = a.w;
  }
  float m = v[0];
#pragma unroll
  for (int j = 1; j < 16; ++j) m = fmaxf(m, v[j]);
#pragma unroll
  for (int o = 32; o; o >>= 1) m = fmaxf(m, __shfl_xor(m, o));
  __shared__ float red[8];
  if ((tid & 63) == 0) red[tid >> 6] = m;
  __syncthreads();
  m = fmaxf(fmaxf(red[0], red[1]), fmaxf(red[2], red[3]));
  float s = 0.f;
#pragma unroll
  for (int j = 0; j < 16; ++j) s += __expf(v[j] - m);
#pragma unroll
  for (int o = 32; o; o >>= 1) s += __shfl_xor(s, o);
  if ((tid & 63) == 0) red[4 + (tid >> 6)] = s;
  __syncthreads();
  if (tid == 0) {
    s = (red[4] + red[5]) + (red[6] + red[7]);
    stats[row] = make_float2(m, 1.f / s);
  }
}

// ---------------- fused softmax + transpose: out[e][d] = sm(in)[d][e] ----------------
__global__ __launch_bounds__(256) void transposeSM(const float* __restrict__ in,
                                                   const float2* __restrict__ stats,
                                                   uint16_t* __restrict__ out) {
  __shared__ uint16_t t[64][68];
  __shared__ float2 st[64];
  const int tid = threadIdx.x;
  const int bx = blockIdx.x, by = blockIdx.y;
  if (tid < 64) st[tid] = stats[by * 64 + tid];
  __syncthreads();
  const int tr = tid >> 4;
  const int tc4 = (tid & 15) * 4;
#pragma unroll
  for (int i = 0; i < 4; ++i) {
    const int r = tr + i * 16;
    const float2 ms = st[r];
    float4 v = *(const float4*)&in[(long)(by * 64 + r) * 4096 + bx * 64 + tc4];
    t[r][tc4 + 0] = f2bf_u(__expf(v.x - ms.x) * ms.y);
    t[r][tc4 + 1] = f2bf_u(__expf(v.y - ms.x) * ms.y);
    t[r][tc4 + 2] = f2bf_u(__expf(v.z - ms.x) * ms.y);
    t[r][tc4 + 3] = f2bf_u(__expf(v.w - ms.x) * ms.y);
  }
  __syncthreads();
#pragma unroll
  for (int i = 0; i < 4; ++i) {
    const int oc = tr + i * 16;
    ushort4 v = make_ushort4(t[tc4 + 0][oc], t[tc4 + 1][oc], t[tc4 + 2][oc], t[tc4 + 3][oc]);
    *(ushort4*)&out[(long)(bx * 64 + oc) * 4096 + by * 64 + tc4] = v;
  }
}

// ---------------- host ----------------
extern "C" void kernel_launch(void* const* d_in, const int* in_sizes, int n_in,
                              void* d_out, int out_size, void* d_ws, size_t ws_size,
                              hipStream_t stream) {
  const float* x  = (const float*)d_in[0];
  const float* W1 = (const float*)d_in[1];
  const float* W2 = (const float*)d_in[2];
  const float* W3 = (const float*)d_in[3];
  const float* W4 = (const float*)d_in[4];
  const float* Wo = (const float*)d_in[5];

  char* ws = (char*)d_ws;
  const long SD  = (long)SEQ * DIM;
  const long BSD = (long)NB * SD;
  const long DD  = (long)DIM * DIM;

  // workspace layout (436,207,616 bytes == proven footprint)
  bf16_t* xbf  = (bf16_t*)(ws + 0L);           // x bf16; later y_in bf16
  bf16_t* xAT  = (bf16_t*)(ws + 67108864L);    // xA^T [b][d][s]
  bf16_t* xBT  = (bf16_t*)(ws + 134217728L);   // xB^T [b][e][s]; later xO_sm
  void*   R3   = (void*)  (ws + 201326592L);   // SQ fp32 (per batch); later xC bf16
  bf16_t* Wbf  = (bf16_t*)(ws + 268435456L);   // current weight bf16
  bf16_t* sqmT = (bf16_t*)(ws + 301989888L);   // softmax(sq)^T bf16 [4][e][d]
  float2* stats = (float2*)d_out;              // transient per-batch row stats
  float*  xOraw = (float*)d_out;               // xO raw fp32 (full d_out)
  (void)ws_size; (void)in_sizes; (void)n_in; (void)out_size;

  cvt_f32_bf16_k<<<2048, 256, 0, stream>>>(x, (uint16_t*)xbf, BSD);

  // xA^T[b][d][s] = W1 @ x_b^T   (batched, grid.y = 4)
  cvt_f32_bf16_k<<<2048, 256, 0, stream>>>(W1, (uint16_t*)Wbf, DD);
  gemm256<0><<<dim3(128, 4), 512, 0, stream>>>(Wbf, xbf, (void*)xAT, nullptr,
                                               DIM, SEQ, DIM, 0, SD, SD);
  // xB^T
  cvt_f32_bf16_k<<<2048, 256, 0, stream>>>(W2, (uint16_t*)Wbf, DD);
  gemm256<0><<<dim3(128, 4), 512, 0, stream>>>(Wbf, xbf, (void*)xBT, nullptr,
                                               DIM, SEQ, DIM, 0, SD, SD);

  // per batch: SQ = xA^T @ xB, softmax rows, transposed bf16 -> sqmT[b]
  for (int b = 0; b < NB; ++b) {
    gemm256<1><<<dim3(256, 1), 512, 0, stream>>>(xAT + b * SD, xBT + b * SD, R3, nullptr,
                                                 DIM, DIM, SEQ, 0, 0, 0);
    rowstat4096<<<DIM, 256, 0, stream>>>((const float*)R3, stats);
    transposeSM<<<dim3(64, 64), 256, 0, stream>>>((const float*)R3, stats,
                                                  (uint16_t*)(sqmT + b * DD));
  }

  // xC = x @ W3^T  (batch folded into M) -> R3 (SQ scratch dead)
  cvt_f32_bf16_k<<<2048, 256, 0, stream>>>(W3, (uint16_t*)Wbf, DD);
  gemm256<0><<<dim3(512, 1), 512, 0, stream>>>(xbf, Wbf, R3, nullptr,
                                               NB * SEQ, DIM, DIM, 0, 0, 0);

  // xO[b][s][e] = xC_b @ sqmT_b^T  (batched) -> d_out fp32 scratch
  gemm256<1><<<dim3(128, 4), 512, 0, stream>>>((const bf16_t*)R3, sqmT, (void*)xOraw, nullptr,
                                               SEQ, DIM, DIM, SD, DD, SD);
  // softmax rows of xO -> xO_sm bf16 (overwrites xBT)
  softmax_row4096<<<NB * SEQ, 256, 0, stream>>>(xOraw, (uint16_t*)xBT);

  // y_in = bf16( x + silu(xO_sm @ W4^T) ) -> xbf region
  cvt_f32_bf16_k<<<2048, 256, 0, stream>>>(W4, (uint16_t*)Wbf, DD);
  gemm256<2><<<dim3(512, 1), 512, 0, stream>>>(xBT, Wbf, (void*)xbf, x,
                                               NB * SEQ, DIM, DIM, 0, 0, 0);

  // out = y_in @ Wo^T (fp32)
  cvt_f32_bf16_k<<<2048, 256, 0, stream>>>(Wo, (uint16_t*)Wbf, DD);
  gemm256<1><<<dim3(512, 1), 512, 0, stream>>>(xbf, Wbf, d_out, nullptr,
                                               NB * SEQ, DIM, DIM, 0, 0, 0);
}